// Round 12
// baseline (129.742 us; speedup 1.0000x reference)
//
#include <hip/hip_runtime.h>

#define B 4
#define V 8192
#define F 16384
#define P 4
#define E 2048
#define NPAIR 16

// ws layout (float indices)
#define WS_PTS   0          // NPAIR*V float4 (-2px,-2py,|p|^2,0) = 524288
#define WS_ER    524288     // NPAIR*E float4 (ex,ey,|e|^2,0) = 131072
#define WS_VP    655360     // 16 slots x NPAIR*V partial v-mins = 2097152
#define WS_EP    2752512    // 64 slots x NPAIR*E partial e-mins = 2097152
#define WS_LSQP  4849664    // 128 per-block lsq partials
#define WS_VOLPX 4849792    // 256 per-block vol-x partials
#define WS_VOLPY 4850048    // 256 per-block vol-y partials
#define WS_CX    4850304    // NPAIR chamfer-x accum (zeroed in k_pre)
#define WS_CY    4850320    // NPAIR chamfer-y accum
#define WS_CNT   4850336    // completion counter (uint, zeroed in k_pre)

__device__ __forceinline__ float block_sum(float v, float* sred) {
    #pragma unroll
    for (int off = 32; off; off >>= 1) v += __shfl_down(v, off, 64);
    int w = threadIdx.x >> 6, l = threadIdx.x & 63;
    if (l == 0) sred[w] = v;
    __syncthreads();
    float r = 0.f;
    if (threadIdx.x == 0) {
        r = sred[0];
        for (int i = 1; i < 4; ++i) r += sred[i];
    }
    __syncthreads();
    return r;  // valid on thread 0 only
}

__device__ __forceinline__ float facevol(const float* __restrict__ vb,
                                         int i0, int i1, int i2) {
    float a0 = vb[i0 * 3], a1 = vb[i0 * 3 + 1], a2 = vb[i0 * 3 + 2];
    float b0 = vb[i1 * 3], b1 = vb[i1 * 3 + 1], b2 = vb[i1 * 3 + 2];
    float c0 = vb[i2 * 3], c1 = vb[i2 * 3 + 1], c2 = vb[i2 * 3 + 2];
    float cx = a1 * b2 - a2 * b1;
    float cy = a2 * b0 - a0 * b2;
    float cz = a0 * b1 - a1 * b0;
    return (cx * c0 + cy * c1 + cz * c2) * (1.0f / 6.0f);
}

// Fused: [0,128) proj+lsq, [128,384) volumes, [384,512) build ER + zero accums/counter.
__global__ void __launch_bounds__(256) k_pre(const float* __restrict__ xs,
                                             const float* __restrict__ y,
                                             const float* __restrict__ pm,
                                             const float* __restrict__ em,
                                             const int* __restrict__ faces,
                                             float* __restrict__ ws) {
    __shared__ float spm[48];
    __shared__ float sred[4];
    int tid = threadIdx.x;
    int blk = blockIdx.x;

    if (blk < 128) {                          // ---- projection + lsq
        if (tid < 48) spm[tid] = pm[tid];
        __syncthreads();
        int b = blk >> 5;                     // 32 blocks per batch
        int v = ((blk & 31) << 8) + tid;
        size_t base = ((size_t)b * V + v) * 3;
        float y0 = y[base], y1 = y[base + 1], y2 = y[base + 2];
        float x0 = xs[base], x1 = xs[base + 1], x2 = xs[base + 2];
        float d0 = x0 - y0, d1 = x1 - y1, d2 = x2 - y2;
        float lsq = d0 * d0 + d1 * d1 + d2 * d2;

        float4* pts = (float4*)(ws + WS_PTS);
        #pragma unroll
        for (int p = 0; p < P; ++p) {
            const float* m = spm + p * 12;
            float xw = m[0] * y0 + m[1] * y1 + m[2]  * y2 + m[3];
            float yw = m[4] * y0 + m[5] * y1 + m[6]  * y2 + m[7];
            float w  = m[8] * y0 + m[9] * y1 + m[10] * y2 + m[11];
            float px = xw / w, py = yw / w;
            pts[(size_t)(b * P + p) * V + v] =
                make_float4(-2.f * px, -2.f * py, px * px + py * py, 0.f);
        }
        float s = block_sum(lsq, sred);
        if (tid == 0) ws[WS_LSQP + blk] = s;
    } else if (blk < 384) {                   // ---- face volumes
        int blk2 = blk - 128;
        int b = blk2 >> 6;                    // 64 blocks per batch
        int f = ((blk2 & 63) << 8) + tid;
        size_t fb = ((size_t)b * F + f) * 3;
        int i0 = faces[fb], i1 = faces[fb + 1], i2 = faces[fb + 2];
        const float* xb = xs + (size_t)b * V * 3;
        const float* yb = y  + (size_t)b * V * 3;
        float sx = block_sum(facevol(xb, i0, i1, i2), sred);
        float sy = block_sum(facevol(yb, i0, i1, i2), sred);
        if (tid == 0) { ws[WS_VOLPX + blk2] = sx; ws[WS_VOLPY + blk2] = sy; }
    } else {                                  // ---- build ER, zero accums + counter
        int i = (blk - 384) * 256 + tid;      // [0, 32768)
        float2 e = ((const float2*)em)[i];
        ((float4*)(ws + WS_ER))[i] =
            make_float4(e.x, e.y, e.x * e.x + e.y * e.y, 0.f);
        if (blk == 384) {
            if (tid < 32) ws[WS_CX + tid] = 0.f;              // CX[16]+CY[16]
            if (tid == 32) ((unsigned*)(ws + WS_CNT))[0] = 0; // done-counter
        }
    }
}

// Chamfer, atomic-free, 2048 blocks (8/CU):
//  [0,1024): cham_x — thread owns 8 v's in regs, streams 128 e's via LDS broadcast;
//            partial min per v -> plain store to VP[ech] slot.
//  [1024,2048): cham_y — thread owns 8 e's, streams 128 v's; store to EP[vch] slot.
__global__ void __launch_bounds__(256) k_cham(float* __restrict__ ws) {
    __shared__ float4 sbuf[128];              // 2 KB streamed chunk
    int tid = threadIdx.x;
    int blk = blockIdx.x;

    if (blk < 1024) {                         // ---- cham_x
        int pair = blk >> 6;                  // 64 blocks/pair = vch(4) x ech(16)
        int vch = (blk >> 4) & 3;
        int ech = blk & 15;
        if (tid < 128)
            sbuf[tid] = ((const float4*)(ws + WS_ER))[(size_t)pair * E + ech * 128 + tid];

        const float4* pts = (const float4*)(ws + WS_PTS) + (size_t)pair * V + vch * 2048 + tid;
        float px2[8], py2[8], pz[8], mn[8];
        #pragma unroll
        for (int k = 0; k < 8; ++k) {
            float4 p = pts[k * 256];          // (-2px, -2py, |p|^2, 0)
            px2[k] = p.x; py2[k] = p.y; pz[k] = p.z;
            mn[k] = 3.4e38f;
        }
        __syncthreads();
        #pragma unroll 4
        for (int i = 0; i < 128; ++i) {
            float4 e = sbuf[i];               // wave-uniform broadcast (ex,ey,|e|^2)
            #pragma unroll
            for (int k = 0; k < 8; ++k)
                mn[k] = fminf(mn[k], fmaf(px2[k], e.x, fmaf(py2[k], e.y, e.z)));
        }
        float* vp = ws + WS_VP + (size_t)ech * (NPAIR * V) + (size_t)pair * V + vch * 2048 + tid;
        #pragma unroll
        for (int k = 0; k < 8; ++k)
            vp[k * 256] = mn[k] + pz[k];      // plain store, no atomics
    } else {                                  // ---- cham_y
        int blk2 = blk - 1024;
        int pair = blk2 >> 6;                 // 64 blocks/pair = vch(64)
        int vch = blk2 & 63;
        if (tid < 128)
            sbuf[tid] = ((const float4*)(ws + WS_PTS))[(size_t)pair * V + vch * 128 + tid];

        const float4* er = (const float4*)(ws + WS_ER) + (size_t)pair * E + tid;
        float ex[8], ey[8], ez[8], mn[8];
        #pragma unroll
        for (int k = 0; k < 8; ++k) {
            float4 e = er[k * 256];           // (ex, ey, |e|^2)
            ex[k] = e.x; ey[k] = e.y; ez[k] = e.z;
            mn[k] = 3.4e38f;
        }
        __syncthreads();
        #pragma unroll 4
        for (int i = 0; i < 128; ++i) {
            float4 p = sbuf[i];               // broadcast (-2px, -2py, |p|^2)
            #pragma unroll
            for (int k = 0; k < 8; ++k)
                mn[k] = fminf(mn[k], fmaf(ex[k], p.x, fmaf(ey[k], p.y, p.z)));
        }
        float* ep = ws + WS_EP + (size_t)vch * (NPAIR * E) + (size_t)pair * E + tid;
        #pragma unroll
        for (int k = 0; k < 8; ++k)
            ep[k * 256] = mn[k] + ez[k];      // plain store, no atomics
    }
}

// 640 blocks: fold partial mins -> CX/CY; last block to finish combines -> out.
__global__ void __launch_bounds__(256) k_redout(float* __restrict__ ws,
                                                float* __restrict__ out) {
    __shared__ float sred[4];
    __shared__ unsigned s_rank;
    int tid = threadIdx.x;
    int blk = blockIdx.x;
    float val;
    float* dst;
    if (blk < 512) {                          // VP fold: 16 slots
        int pair = blk >> 5;                  // 32 blocks per pair
        int vidx = (blk & 31) * 256 + tid;
        const float* vp = ws + WS_VP + (size_t)pair * V + vidx;
        float m = vp[0];
        #pragma unroll
        for (int s = 1; s < 16; ++s) m = fminf(m, vp[(size_t)s * (NPAIR * V)]);
        val = m * (1.0f / V);
        dst = ws + WS_CX + pair;
    } else {                                  // EP fold: 64 slots
        int blk2 = blk - 512;
        int pair = blk2 >> 3;                 // 8 blocks per pair
        int eidx = (blk2 & 7) * 256 + tid;
        const float* ep = ws + WS_EP + (size_t)pair * E + eidx;
        float m = ep[0];
        #pragma unroll
        for (int s = 1; s < 64; ++s) m = fminf(m, ep[(size_t)s * (NPAIR * E)]);
        val = m * (1.0f / E);
        dst = ws + WS_CY + pair;
    }
    float s = block_sum(val, sred);
    if (tid == 0) {
        atomicAdd(dst, s);
        __threadfence();                      // make CX/CY visible device-wide
        s_rank = atomicAdd((unsigned*)(ws + WS_CNT), 1u);
    }
    __syncthreads();
    if (s_rank == 639u) {                     // last block: final combine
        __threadfence();                      // acquire: see all CX/CY adds
        for (int b = 0; b < B; ++b) {
            float c = (tid < P) ? (ws[WS_CX + b * P + tid] + ws[WS_CY + b * P + tid]) : 0.f;
            float cham = block_sum(c, sred);
            float volx = block_sum((tid < 64) ? ws[WS_VOLPX + b * 64 + tid] : 0.f, sred);
            float voly = block_sum((tid < 64) ? ws[WS_VOLPY + b * 64 + tid] : 0.f, sred);
            float lsq  = block_sum((tid < 32) ? ws[WS_LSQP  + b * 32 + tid] : 0.f, sred);
            if (tid == 0) {
                float dv = fabsf(voly) - fabsf(volx);
                out[b] = cham * (1.0f / P) + lsq + dv * dv;
            }
        }
    }
}

extern "C" void kernel_launch(void* const* d_in, const int* in_sizes, int n_in,
                              void* d_out, int out_size, void* d_ws, size_t ws_size,
                              hipStream_t stream) {
    const float* xs    = (const float*)d_in[0];
    const float* y     = (const float*)d_in[1];
    const float* pm    = (const float*)d_in[2];
    const float* em    = (const float*)d_in[3];
    const int*   faces = (const int*)d_in[4];
    float* ws  = (float*)d_ws;
    float* out = (float*)d_out;

    hipLaunchKernelGGL(k_pre,    dim3(512),  dim3(256), 0, stream, xs, y, pm, em, faces, ws);
    hipLaunchKernelGGL(k_cham,   dim3(2048), dim3(256), 0, stream, ws);
    hipLaunchKernelGGL(k_redout, dim3(640),  dim3(256), 0, stream, ws, out);
}

// Round 13
// 129.267 us; speedup vs baseline: 1.0037x; 1.0037x over previous
//
#include <hip/hip_runtime.h>

#define B 4
#define V 8192
#define F 16384
#define P 4
#define E 2048
#define NPAIR 16

// ws layout (float indices)
#define WS_PTS   0          // NPAIR*V float4 (-2px,-2py,|p|^2,0) = 524288
#define WS_ER    524288     // NPAIR*E float4 (ex,ey,|e|^2,0) = 131072
#define WS_VP    655360     // 16 slots x NPAIR*V partial v-mins = 2097152
#define WS_EP    2752512    // 64 slots x NPAIR*E partial e-mins = 2097152
#define WS_LSQP  4849664    // 128 per-block lsq partials
#define WS_VOLPX 4849792    // 256 per-block vol-x partials
#define WS_VOLPY 4850048    // 256 per-block vol-y partials
#define WS_CX    4850304    // NPAIR chamfer-x accum (zeroed in k_pre)
#define WS_CY    4850320    // NPAIR chamfer-y accum
#define WS_CNT   4850336    // completion counter (uint, zeroed in k_pre)

__device__ __forceinline__ float block_sum(float v, float* sred) {
    #pragma unroll
    for (int off = 32; off; off >>= 1) v += __shfl_down(v, off, 64);
    int w = threadIdx.x >> 6, l = threadIdx.x & 63;
    if (l == 0) sred[w] = v;
    __syncthreads();
    float r = 0.f;
    if (threadIdx.x == 0) {
        r = sred[0];
        for (int i = 1; i < 4; ++i) r += sred[i];
    }
    __syncthreads();
    return r;  // valid on thread 0 only
}

__device__ __forceinline__ float facevol(const float* __restrict__ vb,
                                         int i0, int i1, int i2) {
    float a0 = vb[i0 * 3], a1 = vb[i0 * 3 + 1], a2 = vb[i0 * 3 + 2];
    float b0 = vb[i1 * 3], b1 = vb[i1 * 3 + 1], b2 = vb[i1 * 3 + 2];
    float c0 = vb[i2 * 3], c1 = vb[i2 * 3 + 1], c2 = vb[i2 * 3 + 2];
    float cx = a1 * b2 - a2 * b1;
    float cy = a2 * b0 - a0 * b2;
    float cz = a0 * b1 - a1 * b0;
    return (cx * c0 + cy * c1 + cz * c2) * (1.0f / 6.0f);
}

// Fused: [0,128) proj+lsq, [128,384) volumes, [384,512) build ER + zero accums/counter.
__global__ void __launch_bounds__(256) k_pre(const float* __restrict__ xs,
                                             const float* __restrict__ y,
                                             const float* __restrict__ pm,
                                             const float* __restrict__ em,
                                             const int* __restrict__ faces,
                                             float* __restrict__ ws) {
    __shared__ float spm[48];
    __shared__ float sred[4];
    int tid = threadIdx.x;
    int blk = blockIdx.x;

    if (blk < 128) {                          // ---- projection + lsq
        if (tid < 48) spm[tid] = pm[tid];
        __syncthreads();
        int b = blk >> 5;                     // 32 blocks per batch
        int v = ((blk & 31) << 8) + tid;
        size_t base = ((size_t)b * V + v) * 3;
        float y0 = y[base], y1 = y[base + 1], y2 = y[base + 2];
        float x0 = xs[base], x1 = xs[base + 1], x2 = xs[base + 2];
        float d0 = x0 - y0, d1 = x1 - y1, d2 = x2 - y2;
        float lsq = d0 * d0 + d1 * d1 + d2 * d2;

        float4* pts = (float4*)(ws + WS_PTS);
        #pragma unroll
        for (int p = 0; p < P; ++p) {
            const float* m = spm + p * 12;
            float xw = m[0] * y0 + m[1] * y1 + m[2]  * y2 + m[3];
            float yw = m[4] * y0 + m[5] * y1 + m[6]  * y2 + m[7];
            float w  = m[8] * y0 + m[9] * y1 + m[10] * y2 + m[11];
            float px = xw / w, py = yw / w;
            pts[(size_t)(b * P + p) * V + v] =
                make_float4(-2.f * px, -2.f * py, px * px + py * py, 0.f);
        }
        float s = block_sum(lsq, sred);
        if (tid == 0) ws[WS_LSQP + blk] = s;
    } else if (blk < 384) {                   // ---- face volumes
        int blk2 = blk - 128;
        int b = blk2 >> 6;                    // 64 blocks per batch
        int f = ((blk2 & 63) << 8) + tid;
        size_t fb = ((size_t)b * F + f) * 3;
        int i0 = faces[fb], i1 = faces[fb + 1], i2 = faces[fb + 2];
        const float* xb = xs + (size_t)b * V * 3;
        const float* yb = y  + (size_t)b * V * 3;
        float sx = block_sum(facevol(xb, i0, i1, i2), sred);
        float sy = block_sum(facevol(yb, i0, i1, i2), sred);
        if (tid == 0) { ws[WS_VOLPX + blk2] = sx; ws[WS_VOLPY + blk2] = sy; }
    } else {                                  // ---- build ER, zero accums + counter
        int i = (blk - 384) * 256 + tid;      // [0, 32768)
        float2 e = ((const float2*)em)[i];
        ((float4*)(ws + WS_ER))[i] =
            make_float4(e.x, e.y, e.x * e.x + e.y * e.y, 0.f);
        if (blk == 384) {
            if (tid < 32) ws[WS_CX + tid] = 0.f;              // CX[16]+CY[16]
            if (tid == 32) ((unsigned*)(ws + WS_CNT))[0] = 0; // done-counter
        }
    }
}

// Chamfer, atomic-free, 2048 blocks (8/CU). Inner loop processes 2 streamed
// elements per fmin: fminf(mn, fminf(d0,d1)) fuses to v_min3_f32 -> 2.5
// VALU ops/eval instead of 3.
__global__ void __launch_bounds__(256) k_cham(float* __restrict__ ws) {
    __shared__ float4 sbuf[128];              // 2 KB streamed chunk
    int tid = threadIdx.x;
    int blk = blockIdx.x;

    if (blk < 1024) {                         // ---- cham_x
        int pair = blk >> 6;                  // 64 blocks/pair = vch(4) x ech(16)
        int vch = (blk >> 4) & 3;
        int ech = blk & 15;
        if (tid < 128)
            sbuf[tid] = ((const float4*)(ws + WS_ER))[(size_t)pair * E + ech * 128 + tid];

        const float4* pts = (const float4*)(ws + WS_PTS) + (size_t)pair * V + vch * 2048 + tid;
        float px2[8], py2[8], pz[8], mn[8];
        #pragma unroll
        for (int k = 0; k < 8; ++k) {
            float4 p = pts[k * 256];          // (-2px, -2py, |p|^2, 0)
            px2[k] = p.x; py2[k] = p.y; pz[k] = p.z;
            mn[k] = 3.4e38f;
        }
        __syncthreads();
        #pragma unroll 2
        for (int i = 0; i < 128; i += 2) {
            float4 e0 = sbuf[i];              // wave-uniform broadcast (ex,ey,|e|^2)
            float4 e1 = sbuf[i + 1];
            #pragma unroll
            for (int k = 0; k < 8; ++k) {
                float d0 = fmaf(px2[k], e0.x, fmaf(py2[k], e0.y, e0.z));
                float d1 = fmaf(px2[k], e1.x, fmaf(py2[k], e1.y, e1.z));
                mn[k] = fminf(mn[k], fminf(d0, d1));   // -> v_min3_f32
            }
        }
        float* vp = ws + WS_VP + (size_t)ech * (NPAIR * V) + (size_t)pair * V + vch * 2048 + tid;
        #pragma unroll
        for (int k = 0; k < 8; ++k)
            vp[k * 256] = mn[k] + pz[k];      // plain store, no atomics
    } else {                                  // ---- cham_y
        int blk2 = blk - 1024;
        int pair = blk2 >> 6;                 // 64 blocks/pair = vch(64)
        int vch = blk2 & 63;
        if (tid < 128)
            sbuf[tid] = ((const float4*)(ws + WS_PTS))[(size_t)pair * V + vch * 128 + tid];

        const float4* er = (const float4*)(ws + WS_ER) + (size_t)pair * E + tid;
        float ex[8], ey[8], ez[8], mn[8];
        #pragma unroll
        for (int k = 0; k < 8; ++k) {
            float4 e = er[k * 256];           // (ex, ey, |e|^2)
            ex[k] = e.x; ey[k] = e.y; ez[k] = e.z;
            mn[k] = 3.4e38f;
        }
        __syncthreads();
        #pragma unroll 2
        for (int i = 0; i < 128; i += 2) {
            float4 p0 = sbuf[i];              // broadcast (-2px, -2py, |p|^2)
            float4 p1 = sbuf[i + 1];
            #pragma unroll
            for (int k = 0; k < 8; ++k) {
                float d0 = fmaf(ex[k], p0.x, fmaf(ey[k], p0.y, p0.z));
                float d1 = fmaf(ex[k], p1.x, fmaf(ey[k], p1.y, p1.z));
                mn[k] = fminf(mn[k], fminf(d0, d1));   // -> v_min3_f32
            }
        }
        float* ep = ws + WS_EP + (size_t)vch * (NPAIR * E) + (size_t)pair * E + tid;
        #pragma unroll
        for (int k = 0; k < 8; ++k)
            ep[k * 256] = mn[k] + ez[k];      // plain store, no atomics
    }
}

// 640 blocks: fold partial mins -> CX/CY; last block to finish combines -> out.
__global__ void __launch_bounds__(256) k_redout(float* __restrict__ ws,
                                                float* __restrict__ out) {
    __shared__ float sred[4];
    __shared__ unsigned s_rank;
    int tid = threadIdx.x;
    int blk = blockIdx.x;
    float val;
    float* dst;
    if (blk < 512) {                          // VP fold: 16 slots
        int pair = blk >> 5;                  // 32 blocks per pair
        int vidx = (blk & 31) * 256 + tid;
        const float* vp = ws + WS_VP + (size_t)pair * V + vidx;
        float m = vp[0];
        #pragma unroll
        for (int s = 1; s < 16; ++s) m = fminf(m, vp[(size_t)s * (NPAIR * V)]);
        val = m * (1.0f / V);
        dst = ws + WS_CX + pair;
    } else {                                  // EP fold: 64 slots
        int blk2 = blk - 512;
        int pair = blk2 >> 3;                 // 8 blocks per pair
        int eidx = (blk2 & 7) * 256 + tid;
        const float* ep = ws + WS_EP + (size_t)pair * E + eidx;
        float m = ep[0];
        #pragma unroll
        for (int s = 1; s < 64; ++s) m = fminf(m, ep[(size_t)s * (NPAIR * E)]);
        val = m * (1.0f / E);
        dst = ws + WS_CY + pair;
    }
    float s = block_sum(val, sred);
    if (tid == 0) {
        atomicAdd(dst, s);
        __threadfence();                      // make CX/CY visible device-wide
        s_rank = atomicAdd((unsigned*)(ws + WS_CNT), 1u);
    }
    __syncthreads();
    if (s_rank == 639u) {                     // last block: final combine
        __threadfence();                      // acquire: see all CX/CY adds
        for (int b = 0; b < B; ++b) {
            float c = (tid < P) ? (ws[WS_CX + b * P + tid] + ws[WS_CY + b * P + tid]) : 0.f;
            float cham = block_sum(c, sred);
            float volx = block_sum((tid < 64) ? ws[WS_VOLPX + b * 64 + tid] : 0.f, sred);
            float voly = block_sum((tid < 64) ? ws[WS_VOLPY + b * 64 + tid] : 0.f, sred);
            float lsq  = block_sum((tid < 32) ? ws[WS_LSQP  + b * 32 + tid] : 0.f, sred);
            if (tid == 0) {
                float dv = fabsf(voly) - fabsf(volx);
                out[b] = cham * (1.0f / P) + lsq + dv * dv;
            }
        }
    }
}

extern "C" void kernel_launch(void* const* d_in, const int* in_sizes, int n_in,
                              void* d_out, int out_size, void* d_ws, size_t ws_size,
                              hipStream_t stream) {
    const float* xs    = (const float*)d_in[0];
    const float* y     = (const float*)d_in[1];
    const float* pm    = (const float*)d_in[2];
    const float* em    = (const float*)d_in[3];
    const int*   faces = (const int*)d_in[4];
    float* ws  = (float*)d_ws;
    float* out = (float*)d_out;

    hipLaunchKernelGGL(k_pre,    dim3(512),  dim3(256), 0, stream, xs, y, pm, em, faces, ws);
    hipLaunchKernelGGL(k_cham,   dim3(2048), dim3(256), 0, stream, ws);
    hipLaunchKernelGGL(k_redout, dim3(640),  dim3(256), 0, stream, ws, out);
}